// Round 7
// baseline (462.765 us; speedup 1.0000x reference)
//
#include <hip/hip_runtime.h>
#include <hip/hip_fp16.h>

#define DFEAT 64
#define BKT_SHIFT 8            // 256 nodes per bucket
#define BKT_NODES 256
#define NBMAX 512              // supports up to 131072 nodes
#define CH 4096                // edges per partition chunk
#define SRC_BITS 18            // src index bits in packed record
#define SRC_MASK ((1 << SRC_BITS) - 1)

__device__ __forceinline__ unsigned short f2h(float f) {
    return __half_as_ushort(__float2half(f));
}
__device__ __forceinline__ float h2f(unsigned short u) {
    return __half2float(__ushort_as_half(u));
}

// ---------------------------------------------------------------------------
// init: X_out = f16(max(outdeg,1e-8)*H) ; X_in = f16(max(indeg,1e-8)*H);
// thread 0 computes softmax(hop_att)*theta coefs.
// ---------------------------------------------------------------------------
__global__ void init_kernel(const float* __restrict__ H,
                            const float* __restrict__ outdeg,
                            const float* __restrict__ indeg,
                            const float* __restrict__ hop_att,
                            const float* __restrict__ th_out,
                            const float* __restrict__ th_in,
                            unsigned short* __restrict__ XAout,
                            unsigned short* __restrict__ XAin,
                            float* __restrict__ coefs, int n4) {
    int idx = blockIdx.x * blockDim.x + threadIdx.x;
    if (idx == 0) {
        float m = fmaxf(fmaxf(hop_att[0], hop_att[1]), hop_att[2]);
        float e0 = __expf(hop_att[0] - m);
        float e1 = __expf(hop_att[1] - m);
        float e2 = __expf(hop_att[2] - m);
        float inv = 1.0f / (e0 + e1 + e2);
        coefs[0] = e0 * inv * th_out[0]; coefs[1] = e0 * inv * th_in[0];
        coefs[2] = e1 * inv * th_out[1]; coefs[3] = e1 * inv * th_in[1];
        coefs[4] = e2 * inv * th_out[2]; coefs[5] = e2 * inv * th_in[2];
    }
    if (idx >= n4) return;
    int row = idx >> 4;                       // 16 float4 per 64-wide row
    float4 h = reinterpret_cast<const float4*>(H)[idx];
    float doo = fmaxf(outdeg[row], 1e-8f);
    float dii = fmaxf(indeg[row], 1e-8f);
    reinterpret_cast<ushort4*>(XAout)[idx] =
        make_ushort4(f2h(h.x * doo), f2h(h.y * doo), f2h(h.z * doo), f2h(h.w * doo));
    reinterpret_cast<ushort4*>(XAin)[idx] =
        make_ushort4(f2h(h.x * dii), f2h(h.y * dii), f2h(h.z * dii), f2h(h.w * dii));
}

// ---------------------------------------------------------------------------
// hist2d: per-chunk LDS histogram over buckets, both directions.
// ---------------------------------------------------------------------------
__global__ __launch_bounds__(256) void hist2d_kernel(
        const int* __restrict__ erow, const int* __restrict__ ecol,
        int* __restrict__ cnt2, int nEdges, int nB, int nBlkA) {
    __shared__ int hR[NBMAX], hC[NBMAX];
    int k = blockIdx.x;
    for (int i = threadIdx.x; i < nB; i += 256) { hR[i] = 0; hC[i] = 0; }
    __syncthreads();
    int base = k * CH;
    int nV = min(CH, nEdges - base);
    for (int i = threadIdx.x; i < nV; i += 256) {
        atomicAdd(&hR[erow[base + i] >> BKT_SHIFT], 1);
        atomicAdd(&hC[ecol[base + i] >> BKT_SHIFT], 1);
    }
    __syncthreads();
    for (int b = threadIdx.x; b < nB; b += 256) {
        cnt2[(size_t)b * nBlkA + k] = hR[b];
        cnt2[((size_t)nB + b) * nBlkA + k] = hC[b];
    }
}

// ---------------------------------------------------------------------------
// generic hierarchical exclusive scan (single array, in place)
// ---------------------------------------------------------------------------
__global__ void scan_reduce1(const int* __restrict__ p, int* __restrict__ bsum,
                             int n) {
    int t = threadIdx.x, lane = t & 63, wid = t >> 6;
    int base = blockIdx.x * 1024 + t * 4;
    int s = 0;
#pragma unroll
    for (int i = 0; i < 4; ++i) { int idx = base + i; if (idx < n) s += p[idx]; }
#pragma unroll
    for (int o = 32; o >= 1; o >>= 1) s += __shfl_down(s, o, 64);
    __shared__ int wsum[4];
    if (lane == 0) wsum[wid] = s;
    __syncthreads();
    if (t == 0) bsum[blockIdx.x] = wsum[0] + wsum[1] + wsum[2] + wsum[3];
}

__global__ void scan_spine1(int* __restrict__ bsum, int nChunks) {
    int lane = threadIdx.x;                    // single 64-lane wave
    int carry = 0;
    for (int base = 0; base < nChunks; base += 64) {
        int i = base + lane;
        int v = (i < nChunks) ? bsum[i] : 0;
        int s = v;
#pragma unroll
        for (int o = 1; o < 64; o <<= 1) {
            int x = __shfl_up(s, o, 64);
            if (lane >= o) s += x;
        }
        if (i < nChunks) bsum[i] = carry + s - v;
        carry += __shfl(s, 63, 64);
    }
}

__global__ void scan_down1(int* __restrict__ p, const int* __restrict__ bsum,
                           int n) {
    int t = threadIdx.x, lane = t & 63, wid = t >> 6;
    int base = blockIdx.x * 1024 + t * 4;
    int v[4];
    int tsum = 0;
#pragma unroll
    for (int i = 0; i < 4; ++i) {
        v[i] = (base + i < n) ? p[base + i] : 0;
        tsum += v[i];
    }
    int inc = tsum;
#pragma unroll
    for (int o = 1; o < 64; o <<= 1) {
        int x = __shfl_up(inc, o, 64);
        if (lane >= o) inc += x;
    }
    __shared__ int wsum[4];
    if (lane == 63) wsum[wid] = inc;
    __syncthreads();
    int woff = 0;
    for (int w = 0; w < wid; ++w) woff += wsum[w];
    int run = bsum[blockIdx.x] + woff + inc - tsum;
#pragma unroll
    for (int i = 0; i < 4; ++i) {
        if (base + i < n) p[base + i] = run;
        run += v[i];
    }
}

// ---------------------------------------------------------------------------
// partA: LDS-staged radix partition of edges into 256-node buckets.
// ---------------------------------------------------------------------------
__global__ __launch_bounds__(256) void partA_kernel(
        const int* __restrict__ erow, const int* __restrict__ ecol,
        const float* __restrict__ eval, const int* __restrict__ base2,
        int2* __restrict__ recR, int2* __restrict__ recC,
        int nEdges, int nB, int nBlkA) {
    __shared__ int hist[NBMAX], scn[NBMAX], cur[NBMAX], gbase[NBMAX];
    __shared__ unsigned short keybuf[CH], slotKey[CH];
    __shared__ int2 stage[CH];
    int dir = blockIdx.y;
    const int* dk = dir ? ecol : erow;      // dst side (grouping key)
    const int* ds = dir ? erow : ecol;      // src side (payload)
    int2* rec = dir ? recC : recR;
    int k = blockIdx.x;
    int base = k * CH;
    int nV = min(CH, nEdges - base);
    for (int i = threadIdx.x; i < nB; i += 256) {
        hist[i] = 0; cur[i] = 0;
        gbase[i] = base2[((size_t)dir * nB + i) * nBlkA + k] - dir * nEdges;
    }
    __syncthreads();
    for (int i = threadIdx.x; i < nV; i += 256) {
        int key = dk[base + i] >> BKT_SHIFT;
        keybuf[i] = (unsigned short)key;
        atomicAdd(&hist[key], 1);
    }
    __syncthreads();
    if (threadIdx.x < 64) {                 // wave-0 exclusive scan hist->scn
        int lane = threadIdx.x;
        int carry = 0;
        for (int bb = 0; bb < nB; bb += 64) {
            int i = bb + lane;
            int v = (i < nB) ? hist[i] : 0;
            int s = v;
#pragma unroll
            for (int o = 1; o < 64; o <<= 1) {
                int x = __shfl_up(s, o, 64);
                if (lane >= o) s += x;
            }
            if (i < nB) scn[i] = carry + s - v;
            carry += __shfl(s, 63, 64);
        }
    }
    __syncthreads();
    for (int i = threadIdx.x; i < nV; i += 256) {   // compact into LDS
        int e = base + i;
        int key = keybuf[i];
        int slot = scn[key] + atomicAdd(&cur[key], 1);
        int dl = dk[e] & (BKT_NODES - 1);
        stage[slot] = make_int2(ds[e] | (dl << SRC_BITS), __float_as_int(eval[e]));
        slotKey[slot] = (unsigned short)key;
    }
    __syncthreads();
    for (int i = threadIdx.x; i < nV; i += 256) {   // grouped copy-out
        int key = slotKey[i];
        rec[gbase[key] + (i - scn[key])] = stage[i];
    }
}

// ---------------------------------------------------------------------------
// partB: per-bucket exact scatter; emits rowptr/colptr + packed pairs
// (src 17b << 15 | f16-val-sans-sign 15b).
// ---------------------------------------------------------------------------
__global__ __launch_bounds__(256) void partB_kernel(
        const int2* __restrict__ recR, const int2* __restrict__ recC,
        const int* __restrict__ base2,
        int* __restrict__ rowptr, int* __restrict__ colptr,
        unsigned* __restrict__ pairsR, unsigned* __restrict__ pairsC,
        int nEdges, int nB, int nBlkA, int nNodes) {
    __shared__ int hist[BKT_NODES], scn[BKT_NODES], cur[BKT_NODES];
    int dir = blockIdx.y;
    int b = blockIdx.x;
    const int2* rec = dir ? recC : recR;
    unsigned* pairs = dir ? pairsC : pairsR;
    int* nptr = dir ? colptr : rowptr;
    int segB = base2[((size_t)dir * nB + b) * nBlkA] - dir * nEdges;
    int segE = (b == nB - 1) ? nEdges
             : base2[((size_t)dir * nB + b + 1) * nBlkA] - dir * nEdges;
    int t = threadIdx.x;
    hist[t] = 0; cur[t] = 0;
    __syncthreads();
    for (int j = segB + t; j < segE; j += 256)
        atomicAdd(&hist[(rec[j].x >> SRC_BITS) & (BKT_NODES - 1)], 1);
    __syncthreads();
    if (t < 64) {                           // wave-0 exclusive scan (256)
        int lane = t, carry = 0;
        for (int bb = 0; bb < BKT_NODES; bb += 64) {
            int i = bb + lane;
            int v = hist[i], s = v;
#pragma unroll
            for (int o = 1; o < 64; o <<= 1) {
                int x = __shfl_up(s, o, 64);
                if (lane >= o) s += x;
            }
            scn[i] = carry + s - v;
            carry += __shfl(s, 63, 64);
        }
    }
    __syncthreads();
    int node = (b << BKT_SHIFT) + t;
    if (node < nNodes) nptr[node] = segB + scn[t];
    if (b == nB - 1 && t == 0) nptr[nNodes] = nEdges;
    for (int j = segB + t; j < segE; j += 256) {
        int2 r = rec[j];
        int dl = (r.x >> SRC_BITS) & (BKT_NODES - 1);
        int slot = segB + scn[dl] + atomicAdd(&cur[dl], 1);
        unsigned vh = f2h(__int_as_float(r.y)) & 0x7FFFu;   // val>=0: sign bit 0
        pairs[slot] = ((unsigned)(r.x & SRC_MASK) << 15) | vh;
    }
}

// ---------------------------------------------------------------------------
// spmm, direction-split across XCDs: blockIdx%8 in {0..3} -> dir 0 (A @ X,
// gathers Xout only), {4..7} -> dir 1 (A^T @ X, gathers Xin only). With the
// round-robin blockIdx->XCD mapping, each XCD touches ONE 12.8MB table,
// halving the per-XCD L2-fill floor.
// Wave = 1 dst node; 2 edges in flight per step: lanes 0-31 edge j (2 dims
// per lane via half2), lanes 32-63 edge j+1; halves combined by shfl_xor(32).
// Per-direction sum accumulators (sumO/sumI) -> no cross-half race.
// ---------------------------------------------------------------------------
template <int FIRST, int LAST>
__global__ __launch_bounds__(256) void spmm_split(
        const int* __restrict__ rowptr, const unsigned* __restrict__ pairsR,
        const int* __restrict__ colptr, const unsigned* __restrict__ pairsC,
        const __half* __restrict__ Xout, const __half* __restrict__ Xin,
        unsigned short* __restrict__ Yout, unsigned short* __restrict__ Yin,
        unsigned short* __restrict__ sumO, unsigned short* __restrict__ sumI,
        const float* __restrict__ coefs, int k, int nNodes) {
    int b = blockIdx.x;
    int slot = b & 7;
    int dir = slot >> 2;
    int g = (b >> 3) * 4 + (slot & 3);
    int wid = threadIdx.x >> 6;
    int lane = threadIdx.x & 63;
    int node = g * 4 + wid;
    if (node >= nNodes) return;

    const int* ptr = dir ? colptr : rowptr;
    const unsigned* pairs = dir ? pairsC : pairsR;
    const __half* X = dir ? Xin : Xout;
    unsigned short* Y = dir ? Yin : Yout;
    unsigned short* sm = dir ? sumI : sumO;
    float cf = coefs[2 * k + dir];

    int hb = lane >> 5;            // half id: 0 -> edge j, 1 -> edge j+1
    int sub = lane & 31;           // dims 2*sub, 2*sub+1

    float2 a0 = {0.f, 0.f}, a1 = {0.f, 0.f}, a2 = {0.f, 0.f}, a3 = {0.f, 0.f};
    int bE = ptr[node], eE = ptr[node + 1];
    int j = bE;
    for (; j + 8 <= eE; j += 8) {
        unsigned p0 = pairs[j     + hb];
        unsigned p1 = pairs[j + 2 + hb];
        unsigned p2 = pairs[j + 4 + hb];
        unsigned p3 = pairs[j + 6 + hb];
        float2 x0 = __half22float2(*(const __half2*)(X + (p0 >> 15) * DFEAT + 2 * sub));
        float2 x1 = __half22float2(*(const __half2*)(X + (p1 >> 15) * DFEAT + 2 * sub));
        float2 x2 = __half22float2(*(const __half2*)(X + (p2 >> 15) * DFEAT + 2 * sub));
        float2 x3 = __half22float2(*(const __half2*)(X + (p3 >> 15) * DFEAT + 2 * sub));
        float v0 = h2f(p0 & 0x7FFFu);
        float v1 = h2f(p1 & 0x7FFFu);
        float v2 = h2f(p2 & 0x7FFFu);
        float v3 = h2f(p3 & 0x7FFFu);
        a0.x += v0 * x0.x; a0.y += v0 * x0.y;
        a1.x += v1 * x1.x; a1.y += v1 * x1.y;
        a2.x += v2 * x2.x; a2.y += v2 * x2.y;
        a3.x += v3 * x3.x; a3.y += v3 * x3.y;
    }
    if (j < eE) {                  // predicated tail (up to 7 edges)
#pragma unroll
        for (int q = 0; q < 4; ++q) {
            int idx = j + 2 * q + hb;
            unsigned p = (idx < eE) ? pairs[idx] : 0u;   // p=0 -> val 0, src 0
            float2 x = __half22float2(*(const __half2*)(X + (p >> 15) * DFEAT + 2 * sub));
            float v = h2f(p & 0x7FFFu);
            a0.x += v * x.x; a0.y += v * x.y;
        }
    }
    float ax = (a0.x + a1.x) + (a2.x + a3.x);
    float ay = (a0.y + a1.y) + (a2.y + a3.y);
    ax += __shfl_xor(ax, 32, 64);  // combine the two edge-halves
    ay += __shfl_xor(ay, 32, 64);

    if (hb == 0) {                 // lanes 0-31: 4B per lane = 128B row
        int off = node * DFEAT + 2 * sub;
        if (!LAST) {
            __half2 yv = __floats2half2_rn(ax, ay);
            __builtin_nontemporal_store(*reinterpret_cast<unsigned*>(&yv),
                                        reinterpret_cast<unsigned*>(Y + off));
        }
        float sx = cf * ax, sy = cf * ay;
        if (!FIRST) {
            __half2 old = *reinterpret_cast<const __half2*>(sm + off);
            float2 of = __half22float2(old);
            sx += of.x; sy += of.y;
        }
        __half2 sv = __floats2half2_rn(sx, sy);
        __builtin_nontemporal_store(*reinterpret_cast<unsigned*>(&sv),
                                    reinterpret_cast<unsigned*>(sm + off));
    }
}

// ---------------------------------------------------------------------------
// epilogue: out[r][c] = sigmoid(dot(sumO[r,:]+sumI[r,:], Theta[:,c])) + H[r][c]
// ---------------------------------------------------------------------------
__global__ __launch_bounds__(256) void final_kernel(
        const unsigned short* __restrict__ sumO,
        const unsigned short* __restrict__ sumI,
        const float* __restrict__ H, const float* __restrict__ Theta,
        float* __restrict__ out, int nRows) {
    __shared__ float Th[64 * 64];
    __shared__ float Srow[4 * 64];
    int t = threadIdx.x;             // 256 threads
    for (int i = t; i < 64 * 64; i += 256) Th[i] = Theta[i];
    int rl = t >> 6;
    int c = t & 63;
    int row = blockIdx.x * 4 + rl;
    int off = row * DFEAT + c;
    float sv = (row < nRows) ? h2f(sumO[off]) + h2f(sumI[off]) : 0.f;
    Srow[rl * 64 + c] = sv;
    __syncthreads();
    if (row >= nRows) return;
    float acc = 0.f;
#pragma unroll
    for (int kk = 0; kk < 64; ++kk) acc += Srow[rl * 64 + kk] * Th[kk * 64 + c];
    float r = 1.0f / (1.0f + __expf(-acc)) + H[off];
    __builtin_nontemporal_store(r, &out[off]);
}

extern "C" void kernel_launch(void* const* d_in, const int* in_sizes, int n_in,
                              void* d_out, int out_size, void* d_ws, size_t ws_size,
                              hipStream_t stream) {
    const float* H      = (const float*)d_in[0];
    const int*   erow   = (const int*)d_in[1];
    const int*   ecol   = (const int*)d_in[2];
    const float* eval   = (const float*)d_in[3];
    const float* outdeg = (const float*)d_in[4];
    const float* indeg  = (const float*)d_in[5];
    const float* hopatt = (const float*)d_in[6];
    const float* thout  = (const float*)d_in[7];
    const float* thin   = (const float*)d_in[8];
    const float* Theta  = (const float*)d_in[9];
    float* out = (float*)d_out;

    int nNodes = in_sizes[0] / DFEAT;
    int nEdges = in_sizes[1];

    char* ws = (char*)d_ws;
    size_t off = 0;
    auto alloc = [&](size_t bytes) {
        void* p = ws + off;
        off += (bytes + 255) & ~(size_t)255;
        return p;
    };
    size_t xBytes = (size_t)nNodes * DFEAT * sizeof(unsigned short);
    unsigned short* XAout = (unsigned short*)alloc(xBytes);
    unsigned short* XAin  = (unsigned short*)alloc(xBytes);
    unsigned short* XBout = (unsigned short*)alloc(xBytes);
    unsigned short* XBin  = (unsigned short*)alloc(xBytes);
    unsigned short* sumO  = (unsigned short*)alloc(xBytes);
    unsigned short* sumI  = (unsigned short*)alloc(xBytes);
    int*   rowptr = (int*)alloc((size_t)(nNodes + 1) * sizeof(int));
    int*   colptr = (int*)alloc((size_t)(nNodes + 1) * sizeof(int));
    int2*  recR   = (int2*)alloc((size_t)nEdges * sizeof(int2));
    int2*  recC   = (int2*)alloc((size_t)nEdges * sizeof(int2));
    unsigned* pairsR = (unsigned*)alloc((size_t)nEdges * sizeof(unsigned));
    unsigned* pairsC = (unsigned*)alloc((size_t)nEdges * sizeof(unsigned));

    int nB    = (nNodes + BKT_NODES - 1) >> BKT_SHIFT;
    int nBlkA = (nEdges + CH - 1) / CH;
    int L = 2 * nB * nBlkA;
    int nChunks = (L + 1023) / 1024;
    int*   cnt2 = (int*)alloc((size_t)L * sizeof(int));
    int*   bsum = (int*)alloc((size_t)nChunks * sizeof(int));
    float* coefs = (float*)alloc(8 * sizeof(float));

    int n4 = nNodes * (DFEAT / 4);
    int ewBlocks = (n4 + 255) / 256;
    // direction-split grid: 8 slots/round, slots 0-3 dir0, 4-7 dir1;
    // each dir covers g = 0 .. 4*(grid/8)-1, node = g*4 + wid.
    int gPerDir = (nNodes + 3) / 4;          // wave-groups per direction
    int grid8 = (gPerDir + 3) / 4;           // rounds of 8 blocks
    int splitGrid = 8 * grid8;

    // ---- build phase ----
    init_kernel<<<ewBlocks, 256, 0, stream>>>(H, outdeg, indeg, hopatt, thout, thin,
                                              XAout, XAin, coefs, n4);
    hist2d_kernel<<<nBlkA, 256, 0, stream>>>(erow, ecol, cnt2, nEdges, nB, nBlkA);
    scan_reduce1<<<nChunks, 256, 0, stream>>>(cnt2, bsum, L);
    scan_spine1<<<1, 64, 0, stream>>>(bsum, nChunks);
    scan_down1<<<nChunks, 256, 0, stream>>>(cnt2, bsum, L);
    partA_kernel<<<dim3(nBlkA, 2), 256, 0, stream>>>(erow, ecol, eval, cnt2,
                                                     recR, recC, nEdges, nB, nBlkA);
    partB_kernel<<<dim3(nB, 2), 256, 0, stream>>>(recR, recC, cnt2,
                                                  rowptr, colptr, pairsR, pairsC,
                                                  nEdges, nB, nBlkA, nNodes);

    // ---- hop phase (per-direction sums; XCD-split) ----
    spmm_split<1, 0><<<splitGrid, 256, 0, stream>>>(rowptr, pairsR, colptr, pairsC,
                                                    (const __half*)XAout, (const __half*)XAin,
                                                    XBout, XBin, sumO, sumI,
                                                    coefs, 0, nNodes);
    spmm_split<0, 0><<<splitGrid, 256, 0, stream>>>(rowptr, pairsR, colptr, pairsC,
                                                    (const __half*)XBout, (const __half*)XBin,
                                                    XAout, XAin, sumO, sumI,
                                                    coefs, 1, nNodes);
    spmm_split<0, 1><<<splitGrid, 256, 0, stream>>>(rowptr, pairsR, colptr, pairsC,
                                                    (const __half*)XAout, (const __half*)XAin,
                                                    nullptr, nullptr, sumO, sumI,
                                                    coefs, 2, nNodes);

    // ---- epilogue: sigmoid((sumO+sumI) @ Theta) + H ----
    final_kernel<<<(nNodes + 3) / 4, 256, 0, stream>>>(sumO, sumI, H, Theta,
                                                       out, nNodes);
}

// Round 8
// 412.141 us; speedup vs baseline: 1.1228x; 1.1228x over previous
//
#include <hip/hip_runtime.h>
#include <hip/hip_fp16.h>

#define DFEAT 64
#define BKT_SHIFT 8            // 256 nodes per bucket
#define BKT_NODES 256
#define NBMAX 512              // supports up to 131072 nodes
#define CH 4096                // edges per partition chunk
#define SRC_BITS 18            // src index bits in packed record
#define SRC_MASK ((1 << SRC_BITS) - 1)

__device__ __forceinline__ unsigned short f2h(float f) {
    return __half_as_ushort(__float2half(f));
}
__device__ __forceinline__ float h2f(unsigned short u) {
    return __half2float(__ushort_as_half(u));
}

// ---------------------------------------------------------------------------
// init: X_out = f16(max(outdeg,1e-8)*H) ; X_in = f16(max(indeg,1e-8)*H);
// thread 0 computes softmax(hop_att)*theta coefs.
// ---------------------------------------------------------------------------
__global__ void init_kernel(const float* __restrict__ H,
                            const float* __restrict__ outdeg,
                            const float* __restrict__ indeg,
                            const float* __restrict__ hop_att,
                            const float* __restrict__ th_out,
                            const float* __restrict__ th_in,
                            unsigned short* __restrict__ XAout,
                            unsigned short* __restrict__ XAin,
                            float* __restrict__ coefs, int n4) {
    int idx = blockIdx.x * blockDim.x + threadIdx.x;
    if (idx == 0) {
        float m = fmaxf(fmaxf(hop_att[0], hop_att[1]), hop_att[2]);
        float e0 = __expf(hop_att[0] - m);
        float e1 = __expf(hop_att[1] - m);
        float e2 = __expf(hop_att[2] - m);
        float inv = 1.0f / (e0 + e1 + e2);
        coefs[0] = e0 * inv * th_out[0]; coefs[1] = e0 * inv * th_in[0];
        coefs[2] = e1 * inv * th_out[1]; coefs[3] = e1 * inv * th_in[1];
        coefs[4] = e2 * inv * th_out[2]; coefs[5] = e2 * inv * th_in[2];
    }
    if (idx >= n4) return;
    int row = idx >> 4;                       // 16 float4 per 64-wide row
    float4 h = reinterpret_cast<const float4*>(H)[idx];
    float doo = fmaxf(outdeg[row], 1e-8f);
    float dii = fmaxf(indeg[row], 1e-8f);
    reinterpret_cast<ushort4*>(XAout)[idx] =
        make_ushort4(f2h(h.x * doo), f2h(h.y * doo), f2h(h.z * doo), f2h(h.w * doo));
    reinterpret_cast<ushort4*>(XAin)[idx] =
        make_ushort4(f2h(h.x * dii), f2h(h.y * dii), f2h(h.z * dii), f2h(h.w * dii));
}

// ---------------------------------------------------------------------------
// hist2d: per-chunk LDS histogram over buckets, both directions.
// ---------------------------------------------------------------------------
__global__ __launch_bounds__(256) void hist2d_kernel(
        const int* __restrict__ erow, const int* __restrict__ ecol,
        int* __restrict__ cnt2, int nEdges, int nB, int nBlkA) {
    __shared__ int hR[NBMAX], hC[NBMAX];
    int k = blockIdx.x;
    for (int i = threadIdx.x; i < nB; i += 256) { hR[i] = 0; hC[i] = 0; }
    __syncthreads();
    int base = k * CH;
    int nV = min(CH, nEdges - base);
    for (int i = threadIdx.x; i < nV; i += 256) {
        atomicAdd(&hR[erow[base + i] >> BKT_SHIFT], 1);
        atomicAdd(&hC[ecol[base + i] >> BKT_SHIFT], 1);
    }
    __syncthreads();
    for (int b = threadIdx.x; b < nB; b += 256) {
        cnt2[(size_t)b * nBlkA + k] = hR[b];
        cnt2[((size_t)nB + b) * nBlkA + k] = hC[b];
    }
}

// ---------------------------------------------------------------------------
// generic hierarchical exclusive scan (single array, in place)
// ---------------------------------------------------------------------------
__global__ void scan_reduce1(const int* __restrict__ p, int* __restrict__ bsum,
                             int n) {
    int t = threadIdx.x, lane = t & 63, wid = t >> 6;
    int base = blockIdx.x * 1024 + t * 4;
    int s = 0;
#pragma unroll
    for (int i = 0; i < 4; ++i) { int idx = base + i; if (idx < n) s += p[idx]; }
#pragma unroll
    for (int o = 32; o >= 1; o >>= 1) s += __shfl_down(s, o, 64);
    __shared__ int wsum[4];
    if (lane == 0) wsum[wid] = s;
    __syncthreads();
    if (t == 0) bsum[blockIdx.x] = wsum[0] + wsum[1] + wsum[2] + wsum[3];
}

__global__ void scan_spine1(int* __restrict__ bsum, int nChunks) {
    int lane = threadIdx.x;                    // single 64-lane wave
    int carry = 0;
    for (int base = 0; base < nChunks; base += 64) {
        int i = base + lane;
        int v = (i < nChunks) ? bsum[i] : 0;
        int s = v;
#pragma unroll
        for (int o = 1; o < 64; o <<= 1) {
            int x = __shfl_up(s, o, 64);
            if (lane >= o) s += x;
        }
        if (i < nChunks) bsum[i] = carry + s - v;
        carry += __shfl(s, 63, 64);
    }
}

__global__ void scan_down1(int* __restrict__ p, const int* __restrict__ bsum,
                           int n) {
    int t = threadIdx.x, lane = t & 63, wid = t >> 6;
    int base = blockIdx.x * 1024 + t * 4;
    int v[4];
    int tsum = 0;
#pragma unroll
    for (int i = 0; i < 4; ++i) {
        v[i] = (base + i < n) ? p[base + i] : 0;
        tsum += v[i];
    }
    int inc = tsum;
#pragma unroll
    for (int o = 1; o < 64; o <<= 1) {
        int x = __shfl_up(inc, o, 64);
        if (lane >= o) inc += x;
    }
    __shared__ int wsum[4];
    if (lane == 63) wsum[wid] = inc;
    __syncthreads();
    int woff = 0;
    for (int w = 0; w < wid; ++w) woff += wsum[w];
    int run = bsum[blockIdx.x] + woff + inc - tsum;
#pragma unroll
    for (int i = 0; i < 4; ++i) {
        if (base + i < n) p[base + i] = run;
        run += v[i];
    }
}

// ---------------------------------------------------------------------------
// partA: LDS-staged radix partition of edges into 256-node buckets.
// ---------------------------------------------------------------------------
__global__ __launch_bounds__(256) void partA_kernel(
        const int* __restrict__ erow, const int* __restrict__ ecol,
        const float* __restrict__ eval, const int* __restrict__ base2,
        int2* __restrict__ recR, int2* __restrict__ recC,
        int nEdges, int nB, int nBlkA) {
    __shared__ int hist[NBMAX], scn[NBMAX], cur[NBMAX], gbase[NBMAX];
    __shared__ unsigned short keybuf[CH], slotKey[CH];
    __shared__ int2 stage[CH];
    int dir = blockIdx.y;
    const int* dk = dir ? ecol : erow;      // dst side (grouping key)
    const int* ds = dir ? erow : ecol;      // src side (payload)
    int2* rec = dir ? recC : recR;
    int k = blockIdx.x;
    int base = k * CH;
    int nV = min(CH, nEdges - base);
    for (int i = threadIdx.x; i < nB; i += 256) {
        hist[i] = 0; cur[i] = 0;
        gbase[i] = base2[((size_t)dir * nB + i) * nBlkA + k] - dir * nEdges;
    }
    __syncthreads();
    for (int i = threadIdx.x; i < nV; i += 256) {
        int key = dk[base + i] >> BKT_SHIFT;
        keybuf[i] = (unsigned short)key;
        atomicAdd(&hist[key], 1);
    }
    __syncthreads();
    if (threadIdx.x < 64) {                 // wave-0 exclusive scan hist->scn
        int lane = threadIdx.x;
        int carry = 0;
        for (int bb = 0; bb < nB; bb += 64) {
            int i = bb + lane;
            int v = (i < nB) ? hist[i] : 0;
            int s = v;
#pragma unroll
            for (int o = 1; o < 64; o <<= 1) {
                int x = __shfl_up(s, o, 64);
                if (lane >= o) s += x;
            }
            if (i < nB) scn[i] = carry + s - v;
            carry += __shfl(s, 63, 64);
        }
    }
    __syncthreads();
    for (int i = threadIdx.x; i < nV; i += 256) {   // compact into LDS
        int e = base + i;
        int key = keybuf[i];
        int slot = scn[key] + atomicAdd(&cur[key], 1);
        int dl = dk[e] & (BKT_NODES - 1);
        stage[slot] = make_int2(ds[e] | (dl << SRC_BITS), __float_as_int(eval[e]));
        slotKey[slot] = (unsigned short)key;
    }
    __syncthreads();
    for (int i = threadIdx.x; i < nV; i += 256) {   // grouped copy-out
        int key = slotKey[i];
        rec[gbase[key] + (i - scn[key])] = stage[i];
    }
}

// ---------------------------------------------------------------------------
// partB: per-bucket exact scatter; emits rowptr/colptr + packed pairs
// (src 17b << 15 | f16-val-sans-sign 15b).
// ---------------------------------------------------------------------------
__global__ __launch_bounds__(256) void partB_kernel(
        const int2* __restrict__ recR, const int2* __restrict__ recC,
        const int* __restrict__ base2,
        int* __restrict__ rowptr, int* __restrict__ colptr,
        unsigned* __restrict__ pairsR, unsigned* __restrict__ pairsC,
        int nEdges, int nB, int nBlkA, int nNodes) {
    __shared__ int hist[BKT_NODES], scn[BKT_NODES], cur[BKT_NODES];
    int dir = blockIdx.y;
    int b = blockIdx.x;
    const int2* rec = dir ? recC : recR;
    unsigned* pairs = dir ? pairsC : pairsR;
    int* nptr = dir ? colptr : rowptr;
    int segB = base2[((size_t)dir * nB + b) * nBlkA] - dir * nEdges;
    int segE = (b == nB - 1) ? nEdges
             : base2[((size_t)dir * nB + b + 1) * nBlkA] - dir * nEdges;
    int t = threadIdx.x;
    hist[t] = 0; cur[t] = 0;
    __syncthreads();
    for (int j = segB + t; j < segE; j += 256)
        atomicAdd(&hist[(rec[j].x >> SRC_BITS) & (BKT_NODES - 1)], 1);
    __syncthreads();
    if (t < 64) {                           // wave-0 exclusive scan (256)
        int lane = t, carry = 0;
        for (int bb = 0; bb < BKT_NODES; bb += 64) {
            int i = bb + lane;
            int v = hist[i], s = v;
#pragma unroll
            for (int o = 1; o < 64; o <<= 1) {
                int x = __shfl_up(s, o, 64);
                if (lane >= o) s += x;
            }
            scn[i] = carry + s - v;
            carry += __shfl(s, 63, 64);
        }
    }
    __syncthreads();
    int node = (b << BKT_SHIFT) + t;
    if (node < nNodes) nptr[node] = segB + scn[t];
    if (b == nB - 1 && t == 0) nptr[nNodes] = nEdges;
    for (int j = segB + t; j < segE; j += 256) {
        int2 r = rec[j];
        int dl = (r.x >> SRC_BITS) & (BKT_NODES - 1);
        int slot = segB + scn[dl] + atomicAdd(&cur[dl], 1);
        unsigned vh = f2h(__int_as_float(r.y)) & 0x7FFFu;   // val>=0: sign bit 0
        pairs[slot] = ((unsigned)(r.x & SRC_MASK) << 15) | vh;
    }
}

// ---------------------------------------------------------------------------
// gather_rows: one wave, one dst node, one direction. Lanes 0-31 edge j,
// lanes 32-63 edge j+1; each lane 2 dims via half2. 16-edge main loop
// (8 gathers in flight per half), 8-edge mid, predicated 4x2 tail.
// Returns the full combined (ax, ay) for dims (2*sub, 2*sub+1) on ALL lanes.
// ---------------------------------------------------------------------------
__device__ __forceinline__ void gather_rows(
        const int* __restrict__ ptr, const unsigned* __restrict__ pairs,
        const __half* __restrict__ X, int node, int hb, int sub,
        float& axo, float& ayo) {
    float2 a0{0.f,0.f}, a1{0.f,0.f}, a2{0.f,0.f}, a3{0.f,0.f};
    float2 a4{0.f,0.f}, a5{0.f,0.f}, a6{0.f,0.f}, a7{0.f,0.f};
    int j = ptr[node], eE = ptr[node + 1];
    auto step = [&](int jj, float2& a) {
        unsigned p = pairs[jj + hb];
        float2 x = __half22float2(*(const __half2*)(X + (p >> 15) * DFEAT + 2 * sub));
        float v = h2f(p & 0x7FFFu);
        a.x += v * x.x; a.y += v * x.y;
    };
    for (; j + 16 <= eE; j += 16) {
        step(j, a0);      step(j + 2, a1);  step(j + 4, a2);  step(j + 6, a3);
        step(j + 8, a4);  step(j + 10, a5); step(j + 12, a6); step(j + 14, a7);
    }
    if (j + 8 <= eE) {
        step(j, a0); step(j + 2, a1); step(j + 4, a2); step(j + 6, a3);
        j += 8;
    }
#pragma unroll
    for (int q = 0; q < 4; ++q) {           // predicated tail (<= 7 edges)
        int idx = j + 2 * q + hb;
        unsigned p = (idx < eE) ? pairs[idx] : 0u;   // p=0 -> val 0, src 0
        float2 x = __half22float2(*(const __half2*)(X + (p >> 15) * DFEAT + 2 * sub));
        float v = h2f(p & 0x7FFFu);
        a4.x += v * x.x; a4.y += v * x.y;
    }
    float ax = ((a0.x + a1.x) + (a2.x + a3.x)) + ((a4.x + a5.x) + (a6.x + a7.x));
    float ay = ((a0.y + a1.y) + (a2.y + a3.y)) + ((a4.y + a5.y) + (a6.y + a7.y));
    ax += __shfl_xor(ax, 32, 64);           // combine the two edge-halves
    ay += __shfl_xor(ay, 32, 64);
    axo = ax; ayo = ay;
}

// ---------------------------------------------------------------------------
// hops 0-1: direction-split across XCDs. blockIdx%8 in {0..3} -> dir 0
// (gathers Xout only), {4..7} -> dir 1 (Xin only): each XCD's gather working
// set is ONE 12.8MB table -> less L2 capacity thrash (R7: FETCH 205->168MB).
// ---------------------------------------------------------------------------
template <int FIRST>
__global__ __launch_bounds__(256) void spmm_split(
        const int* __restrict__ rowptr, const unsigned* __restrict__ pairsR,
        const int* __restrict__ colptr, const unsigned* __restrict__ pairsC,
        const __half* __restrict__ Xout, const __half* __restrict__ Xin,
        unsigned short* __restrict__ Yout, unsigned short* __restrict__ Yin,
        unsigned short* __restrict__ sumO, unsigned short* __restrict__ sumI,
        const float* __restrict__ coefs, int k, int nNodes) {
    int b = blockIdx.x;
    int slot = b & 7;
    int dir = slot >> 2;
    int g = (b >> 3) * 4 + (slot & 3);
    int wid = threadIdx.x >> 6;
    int lane = threadIdx.x & 63;
    int node = g * 4 + wid;
    if (node >= nNodes) return;

    const int* ptr = dir ? colptr : rowptr;
    const unsigned* pairs = dir ? pairsC : pairsR;
    const __half* X = dir ? Xin : Xout;
    unsigned short* Y = dir ? Yin : Yout;
    unsigned short* sm = dir ? sumI : sumO;
    float cf = coefs[2 * k + dir];

    int hb = lane >> 5;            // half id: 0 -> edge j, 1 -> edge j+1
    int sub = lane & 31;           // dims 2*sub, 2*sub+1

    float ax, ay;
    gather_rows(ptr, pairs, X, node, hb, sub, ax, ay);

    if (hb == 0) {                 // lanes 0-31: 4B per lane = 128B row
        int off = node * DFEAT + 2 * sub;
        __half2 yv = __floats2half2_rn(ax, ay);
        __builtin_nontemporal_store(*reinterpret_cast<unsigned*>(&yv),
                                    reinterpret_cast<unsigned*>(Y + off));
        float sx = cf * ax, sy = cf * ay;
        if (!FIRST) {
            __half2 old = *reinterpret_cast<const __half2*>(sm + off);
            float2 of = __half22float2(old);
            sx += of.x; sy += of.y;
        }
        __half2 sv = __floats2half2_rn(sx, sy);
        __builtin_nontemporal_store(*reinterpret_cast<unsigned*>(&sv),
                                    reinterpret_cast<unsigned*>(sm + off));
    }
}

// ---------------------------------------------------------------------------
// hop 2: both directions per wave + fused epilogue
//   out = sigmoid((sumO + sumI + co*accO + ci*accI) @ Theta) + H.
// No early return (barrier); dead waves compute node 0, don't store.
// Srow write/read is same-wave only (DS pipe is in-order per wave).
// ---------------------------------------------------------------------------
__global__ __launch_bounds__(256) void spmm_last(
        const int* __restrict__ rowptr, const unsigned* __restrict__ pairsR,
        const int* __restrict__ colptr, const unsigned* __restrict__ pairsC,
        const __half* __restrict__ Xout, const __half* __restrict__ Xin,
        const unsigned short* __restrict__ sumO,
        const unsigned short* __restrict__ sumI,
        const float* __restrict__ H, const float* __restrict__ Theta,
        float* __restrict__ out, const float* __restrict__ coefs,
        int k, int nNodes) {
    __shared__ float Th[64 * 64];
    __shared__ float Srow[4 * 64];
    int wid = threadIdx.x >> 6;
    int lane = threadIdx.x & 63;
    int node = blockIdx.x * 4 + wid;
    bool live = node < nNodes;
    int nodeC = live ? node : 0;

    for (int i = threadIdx.x; i < 64 * 64; i += 256) Th[i] = Theta[i];

    float co = coefs[2 * k], ci = coefs[2 * k + 1];
    int hb = lane >> 5;
    int sub = lane & 31;

    float axO, ayO, axI, ayI;
    gather_rows(rowptr, pairsR, Xout, nodeC, hb, sub, axO, ayO);
    gather_rows(colptr, pairsC, Xin,  nodeC, hb, sub, axI, ayI);

    int off = nodeC * DFEAT + 2 * sub;
    float s0 = h2f(sumO[off])     + h2f(sumI[off])     + co * axO + ci * axI;
    float s1 = h2f(sumO[off + 1]) + h2f(sumI[off + 1]) + co * ayO + ci * ayI;

    __syncthreads();                         // Th visible
    if (hb == 0) {
        Srow[wid * 64 + 2 * sub]     = s0;   // same-wave produce...
        Srow[wid * 64 + 2 * sub + 1] = s1;
    }
    float acc = 0.f;                         // ...same-wave consume
#pragma unroll
    for (int kk = 0; kk < 64; ++kk)
        acc += Srow[wid * 64 + kk] * Th[kk * 64 + lane];
    if (live) {
        float r = 1.0f / (1.0f + __expf(-acc)) + H[nodeC * DFEAT + lane];
        __builtin_nontemporal_store(r, &out[nodeC * DFEAT + lane]);
    }
}

extern "C" void kernel_launch(void* const* d_in, const int* in_sizes, int n_in,
                              void* d_out, int out_size, void* d_ws, size_t ws_size,
                              hipStream_t stream) {
    const float* H      = (const float*)d_in[0];
    const int*   erow   = (const int*)d_in[1];
    const int*   ecol   = (const int*)d_in[2];
    const float* eval   = (const float*)d_in[3];
    const float* outdeg = (const float*)d_in[4];
    const float* indeg  = (const float*)d_in[5];
    const float* hopatt = (const float*)d_in[6];
    const float* thout  = (const float*)d_in[7];
    const float* thin   = (const float*)d_in[8];
    const float* Theta  = (const float*)d_in[9];
    float* out = (float*)d_out;

    int nNodes = in_sizes[0] / DFEAT;
    int nEdges = in_sizes[1];

    char* ws = (char*)d_ws;
    size_t off = 0;
    auto alloc = [&](size_t bytes) {
        void* p = ws + off;
        off += (bytes + 255) & ~(size_t)255;
        return p;
    };
    size_t xBytes = (size_t)nNodes * DFEAT * sizeof(unsigned short);
    unsigned short* XAout = (unsigned short*)alloc(xBytes);
    unsigned short* XAin  = (unsigned short*)alloc(xBytes);
    unsigned short* XBout = (unsigned short*)alloc(xBytes);
    unsigned short* XBin  = (unsigned short*)alloc(xBytes);
    unsigned short* sumO  = (unsigned short*)alloc(xBytes);
    unsigned short* sumI  = (unsigned short*)alloc(xBytes);
    int*   rowptr = (int*)alloc((size_t)(nNodes + 1) * sizeof(int));
    int*   colptr = (int*)alloc((size_t)(nNodes + 1) * sizeof(int));
    int2*  recR   = (int2*)alloc((size_t)nEdges * sizeof(int2));
    int2*  recC   = (int2*)alloc((size_t)nEdges * sizeof(int2));
    unsigned* pairsR = (unsigned*)alloc((size_t)nEdges * sizeof(unsigned));
    unsigned* pairsC = (unsigned*)alloc((size_t)nEdges * sizeof(unsigned));

    int nB    = (nNodes + BKT_NODES - 1) >> BKT_SHIFT;
    int nBlkA = (nEdges + CH - 1) / CH;
    int L = 2 * nB * nBlkA;
    int nChunks = (L + 1023) / 1024;
    int*   cnt2 = (int*)alloc((size_t)L * sizeof(int));
    int*   bsum = (int*)alloc((size_t)nChunks * sizeof(int));
    float* coefs = (float*)alloc(8 * sizeof(float));

    int n4 = nNodes * (DFEAT / 4);
    int ewBlocks = (n4 + 255) / 256;
    int gPerDir = (nNodes + 3) / 4;          // wave-groups per direction
    int grid8 = (gPerDir + 3) / 4;           // rounds of 8 blocks
    int splitGrid = 8 * grid8;
    int nodeBlocks = (nNodes + 3) / 4;

    // ---- build phase ----
    init_kernel<<<ewBlocks, 256, 0, stream>>>(H, outdeg, indeg, hopatt, thout, thin,
                                              XAout, XAin, coefs, n4);
    hist2d_kernel<<<nBlkA, 256, 0, stream>>>(erow, ecol, cnt2, nEdges, nB, nBlkA);
    scan_reduce1<<<nChunks, 256, 0, stream>>>(cnt2, bsum, L);
    scan_spine1<<<1, 64, 0, stream>>>(bsum, nChunks);
    scan_down1<<<nChunks, 256, 0, stream>>>(cnt2, bsum, L);
    partA_kernel<<<dim3(nBlkA, 2), 256, 0, stream>>>(erow, ecol, eval, cnt2,
                                                     recR, recC, nEdges, nB, nBlkA);
    partB_kernel<<<dim3(nB, 2), 256, 0, stream>>>(recR, recC, cnt2,
                                                  rowptr, colptr, pairsR, pairsC,
                                                  nEdges, nB, nBlkA, nNodes);

    // ---- hops 0-1: direction-split, per-direction f16 sums ----
    spmm_split<1><<<splitGrid, 256, 0, stream>>>(rowptr, pairsR, colptr, pairsC,
                                                 (const __half*)XAout, (const __half*)XAin,
                                                 XBout, XBin, sumO, sumI,
                                                 coefs, 0, nNodes);
    spmm_split<0><<<splitGrid, 256, 0, stream>>>(rowptr, pairsR, colptr, pairsC,
                                                 (const __half*)XBout, (const __half*)XBin,
                                                 XAout, XAin, sumO, sumI,
                                                 coefs, 1, nNodes);

    // ---- hop 2: fused both-direction spmm + Theta/sigmoid/residual ----
    spmm_last<<<nodeBlocks, 256, 0, stream>>>(rowptr, pairsR, colptr, pairsC,
                                              (const __half*)XAout, (const __half*)XAin,
                                              sumO, sumI, H, Theta, out,
                                              coefs, 2, nNodes);
}